// Round 10
// baseline (3758.040 us; speedup 1.0000x reference)
//
#include <hip/hip_runtime.h>

#define D 256
#define K_OUT 32
#define L_LAYERS 4
#define NPAD 50048

typedef __attribute__((ext_vector_type(8))) short bf16x8;
typedef __attribute__((ext_vector_type(4))) float f32x4;
typedef __attribute__((address_space(3))) unsigned int lds_u32;
typedef const __attribute__((address_space(1))) unsigned int glb_u32;

__device__ __forceinline__ float sigm(float v) { return 1.f / (1.f + __expf(-v)); }
__device__ __forceinline__ unsigned short f2bf(float f) {
    unsigned u = __float_as_uint(f);
    u = u + 0x7fffu + ((u >> 16) & 1u);
    return (unsigned short)(u >> 16);
}
__device__ __forceinline__ float bf2f(unsigned short s) {
    return __uint_as_float(((unsigned)s) << 16);
}
__device__ __forceinline__ void gload16(const unsigned short* g, unsigned short* l) {
    __builtin_amdgcn_global_load_lds((glb_u32*)g, (lds_u32*)l, 16, 0, 0);
}

// frag id f -> A2/BT2 offset (ushort units): 0-7 A_hi, 8-15 A_lo, 16-27 B_hi, 28-39 B_lo
__device__ __forceinline__ void frag_addr(int f, int bm, int bnd, int lane,
                                          unsigned& off, bool& isA, bool& isG2) {
    if (f < 8) {
        off = (unsigned)(bm + f * 16 + (lane & 15)) * 1024u + ((lane >> 4) << 3);
        isA = true; isG2 = false;
    } else if (f < 16) {
        off = (unsigned)(bm + (f - 8) * 16 + (lane & 15)) * 1024u + 512u + ((lane >> 4) << 3);
        isA = true; isG2 = false;
    } else if (f < 28) {
        int q = f - 16; int gs = q >> 2; int df = q & 3;
        off = (unsigned)(gs * 256 + bnd + df * 16 + (lane & 15)) * 1024u + ((lane >> 4) << 3);
        isA = false; isG2 = (gs == 2);
    } else {
        int q = f - 28; int gs = q >> 2; int df = q & 3;
        off = (unsigned)(gs * 256 + bnd + df * 16 + (lane & 15)) * 1024u + 512u + ((lane >> 4) << 3);
        isA = false; isG2 = (gs == 2);
    }
}

// ---------------- CSR build ----------------
__global__ __launch_bounds__(256) void hist_kernel(const int* __restrict__ dst,
                                                   int* __restrict__ cnt, int E) {
    int idx = blockIdx.x * blockDim.x + threadIdx.x;
    for (int e = idx; e < E; e += gridDim.x * blockDim.x)
        atomicAdd(&cnt[dst[e]], 1);
}

__global__ __launch_bounds__(1024) void scan_kernel(const int* __restrict__ cnt,
                                                    int* __restrict__ rowptr,
                                                    int* __restrict__ cursor, int n) {
    __shared__ int sdata[1024];
    int t = threadIdx.x;
    int chunk = (n + 1023) / 1024;
    int start = t * chunk;
    int end = start + chunk; if (end > n) end = n;
    int s = 0;
    for (int i = start; i < end; i++) s += cnt[i];
    sdata[t] = s;
    __syncthreads();
    for (int off = 1; off < 1024; off <<= 1) {
        int v = (t >= off) ? sdata[t - off] : 0;
        __syncthreads();
        sdata[t] += v;
        __syncthreads();
    }
    int base = sdata[t] - s;
    for (int i = start; i < end; i++) {
        rowptr[i] = base;
        cursor[i] = base;
        base += cnt[i];
    }
    if (end == n && start <= n) rowptr[n] = base;
}

__global__ __launch_bounds__(256) void reorder_kernel(const int* __restrict__ src,
                                                      const int* __restrict__ dst,
                                                      const float* __restrict__ ea,
                                                      int* __restrict__ cursor,
                                                      int* __restrict__ esrc,
                                                      float* __restrict__ eval, int E) {
    int idx = blockIdx.x * blockDim.x + threadIdx.x;
    for (int e = idx; e < E; e += gridDim.x * blockDim.x) {
        int slot = atomicAdd(&cursor[dst[e]], 1);
        esrc[slot] = src[e];
        eval[slot] = ea[e];
    }
}

// ---------------- P[l][k][c3] = (weight[l] @ w_ih^T)[k][c3], 256x768 per layer ----------------
__global__ __launch_bounds__(256) void prep_wih_kernel(const float* __restrict__ weight,
                                                       const float* __restrict__ w_ih,
                                                       float* __restrict__ P) {
    int l = blockIdx.z;
    const float* A = weight + (size_t)l * D * D;
    float* Cdst = P + (size_t)l * 256 * 768;
    __shared__ float As[32][64 + 4];
    __shared__ float Bs[32][64 + 4];
    int tid = threadIdx.x;
    int tx = tid & 15, ty = tid >> 4;
    int bk = blockIdx.x * 64;
    int bn = blockIdx.y * 64;
    float acc[4][4] = {};
    for (int jb = 0; jb < D; jb += 32) {
        #pragma unroll
        for (int i = 0; i < 2; i++) {
            int lin = tid + i * 256;
            int row = lin >> 3;
            int c4 = (lin & 7) << 2;
            float4 v = *(const float4*)&A[(size_t)(bk + row) * D + jb + c4];
            As[c4+0][row]=v.x; As[c4+1][row]=v.y; As[c4+2][row]=v.z; As[c4+3][row]=v.w;
            float4 w = *(const float4*)&w_ih[(size_t)(bn + row) * D + jb + c4];
            Bs[c4+0][row]=w.x; Bs[c4+1][row]=w.y; Bs[c4+2][row]=w.z; Bs[c4+3][row]=w.w;
        }
        __syncthreads();
        #pragma unroll
        for (int jj = 0; jj < 32; jj++) {
            float a[4], b[4];
            *(float4*)a = *(const float4*)&As[jj][ty*4];
            *(float4*)b = *(const float4*)&Bs[jj][tx*4];
            #pragma unroll
            for (int i = 0; i < 4; i++)
                #pragma unroll
                for (int j = 0; j < 4; j++)
                    acc[i][j] += a[i] * b[j];
        }
        __syncthreads();
    }
    #pragma unroll
    for (int i = 0; i < 4; i++)
        *(float4*)&Cdst[(size_t)(bk + ty*4 + i) * 768 + bn + tx*4] =
            make_float4(acc[i][0], acc[i][1], acc[i][2], acc[i][3]);
}

// ---------------- BT2[l][c][k2] bf16: c=g*256+d (g: r,z,ni,nh), k2<512 hi, >=512 lo ----------------
__global__ __launch_bounds__(256) void pack_bt2_kernel(const float* __restrict__ P,
                                                       const float* __restrict__ w_hh,
                                                       unsigned short* __restrict__ BT2) {
    long long idx = (long long)blockIdx.x * 256 + threadIdx.x;   // 4M total
    int l = (int)(idx >> 20);
    int rem = (int)(idx & 1048575);
    int c = rem >> 10;
    int k2 = rem & 1023;
    int g = c >> 8, d = c & 255;
    int k = k2 & 511;
    float val;
    if (k < 256) {
        val = (g == 0) ? P[(size_t)l * 196608 + (size_t)k * 768 + d]
            : (g == 1) ? P[(size_t)l * 196608 + (size_t)k * 768 + 256 + d]
            : (g == 2) ? P[(size_t)l * 196608 + (size_t)k * 768 + 512 + d]
            : 0.f;
    } else {
        int kk = k - 256;
        val = (g == 0) ? w_hh[(size_t)d * D + kk]
            : (g == 1) ? w_hh[(size_t)(256 + d) * D + kk]
            : (g == 3) ? w_hh[(size_t)(512 + d) * D + kk]
            : 0.f;
    }
    unsigned short hi = f2bf(val);
    BT2[idx] = (k2 < 512) ? hi : f2bf(val - bf2f(hi));
}

// ---------------- scalar gather: sx[n] = sum ea * x[src] ----------------
__global__ __launch_bounds__(256) void sgather_kernel(const float* __restrict__ x,
                                                      const int* __restrict__ rowptr,
                                                      const int* __restrict__ esrc,
                                                      const float* __restrict__ eval,
                                                      float* __restrict__ sx, int n) {
    int node = blockIdx.x * blockDim.x + threadIdx.x;
    if (node >= n) return;
    float s = 0.f;
    int end = rowptr[node + 1];
    for (int e = rowptr[node]; e < end; e++) s += eval[e] * x[esrc[e]];
    sx[node] = s;
}

// ---------------- layer 0: rank-2 + GRU epilogue, writes h ----------------
__global__ __launch_bounds__(256) void layer0_kernel(const float* __restrict__ x,
                                                     const float* __restrict__ sx,
                                                     const float* __restrict__ P0,
                                                     const float* __restrict__ w_hh,
                                                     const float* __restrict__ b_ih,
                                                     const float* __restrict__ b_hh,
                                                     float* __restrict__ hout, int M) {
    int node = blockIdx.x * 4 + (threadIdx.x >> 6);
    if (node >= M) return;
    int d0 = (threadIdx.x & 63) * 4;
    float sxn = sx[node], xn = x[node];
    float4 r0 = *(const float4*)&P0[d0];
    float4 z0 = *(const float4*)&P0[256 + d0];
    float4 n0 = *(const float4*)&P0[512 + d0];
    float r1[4], z1[4], n1[4];
    #pragma unroll
    for (int j = 0; j < 4; j++) {
        r1[j] = w_hh[(size_t)(d0 + j) * D];
        z1[j] = w_hh[(size_t)(256 + d0 + j) * D];
        n1[j] = w_hh[(size_t)(512 + d0 + j) * D];
    }
    float4 bir = *(const float4*)&b_ih[d0];
    float4 biz = *(const float4*)&b_ih[256 + d0];
    float4 bin = *(const float4*)&b_ih[512 + d0];
    float4 bhr = *(const float4*)&b_hh[d0];
    float4 bhz = *(const float4*)&b_hh[256 + d0];
    float4 bhn = *(const float4*)&b_hh[512 + d0];
    float rr[4] = {sxn*r0.x + xn*r1[0] + bir.x + bhr.x, sxn*r0.y + xn*r1[1] + bir.y + bhr.y,
                   sxn*r0.z + xn*r1[2] + bir.z + bhr.z, sxn*r0.w + xn*r1[3] + bir.w + bhr.w};
    float zz[4] = {sxn*z0.x + xn*z1[0] + biz.x + bhz.x, sxn*z0.y + xn*z1[1] + biz.y + bhz.y,
                   sxn*z0.z + xn*z1[2] + biz.z + bhz.z, sxn*z0.w + xn*z1[3] + biz.w + bhz.w};
    float ni[4] = {sxn*n0.x + bin.x, sxn*n0.y + bin.y, sxn*n0.z + bin.z, sxn*n0.w + bin.w};
    float nh[4] = {xn*n1[0] + bhn.x, xn*n1[1] + bhn.y, xn*n1[2] + bhn.z, xn*n1[3] + bhn.w};
    float o[4];
    #pragma unroll
    for (int j = 0; j < 4; j++) {
        float r = sigm(rr[j]);
        float z = sigm(zz[j]);
        float nn = tanhf(ni[j] + r * nh[j]);
        float hp = (d0 + j == 0) ? xn : 0.f;
        o[j] = (1.f - z) * nn + z * hp;
    }
    *(float4*)&hout[(size_t)node * D + d0] = make_float4(o[0], o[1], o[2], o[3]);
}

// ---------------- gather + fused h2bf (runs after gru completes; kernel boundary) ----------
__global__ __launch_bounds__(256) void gather_bf_kernel(const float* __restrict__ h,
                                                        const int* __restrict__ rowptr,
                                                        const int* __restrict__ esrc,
                                                        const float* __restrict__ eval,
                                                        unsigned short* __restrict__ A2, int n) {
    int node = (blockIdx.x * 256 + threadIdx.x) >> 6;
    int lane = threadIdx.x & 63;
    if (node >= n) return;
    int beg = rowptr[node], end = rowptr[node + 1];
    float4 acc0 = make_float4(0.f, 0.f, 0.f, 0.f);
    float4 acc1 = make_float4(0.f, 0.f, 0.f, 0.f);
    int e = beg;
    for (; e + 1 < end; e += 2) {
        int s0 = esrc[e], s1 = esrc[e + 1];
        float a0 = eval[e], a1 = eval[e + 1];
        float4 v0 = *(const float4*)&h[(size_t)s0 * D + lane * 4];
        float4 v1 = *(const float4*)&h[(size_t)s1 * D + lane * 4];
        acc0.x += a0 * v0.x; acc0.y += a0 * v0.y; acc0.z += a0 * v0.z; acc0.w += a0 * v0.w;
        acc1.x += a1 * v1.x; acc1.y += a1 * v1.y; acc1.z += a1 * v1.z; acc1.w += a1 * v1.w;
    }
    if (e < end) {
        int s0 = esrc[e];
        float a0 = eval[e];
        float4 v0 = *(const float4*)&h[(size_t)s0 * D + lane * 4];
        acc0.x += a0 * v0.x; acc0.y += a0 * v0.y; acc0.z += a0 * v0.z; acc0.w += a0 * v0.w;
    }
    float4 acc = make_float4(acc0.x + acc1.x, acc0.y + acc1.y, acc0.z + acc1.z, acc0.w + acc1.w);
    ushort4 hi = make_ushort4(f2bf(acc.x), f2bf(acc.y), f2bf(acc.z), f2bf(acc.w));
    ushort4 lo = make_ushort4(f2bf(acc.x - bf2f(hi.x)), f2bf(acc.y - bf2f(hi.y)),
                              f2bf(acc.z - bf2f(hi.z)), f2bf(acc.w - bf2f(hi.w)));
    *(ushort4*)&A2[(size_t)node * 1024 + lane * 4] = hi;
    *(ushort4*)&A2[(size_t)node * 1024 + 512 + lane * 4] = lo;
    float4 hv = *(const float4*)&h[(size_t)node * D + lane * 4];
    ushort4 hh = make_ushort4(f2bf(hv.x), f2bf(hv.y), f2bf(hv.z), f2bf(hv.w));
    ushort4 hl = make_ushort4(f2bf(hv.x - bf2f(hh.x)), f2bf(hv.y - bf2f(hh.y)),
                              f2bf(hv.z - bf2f(hh.z)), f2bf(hv.w - bf2f(hh.w)));
    *(ushort4*)&A2[(size_t)node * 1024 + 256 + lane * 4] = hh;
    *(ushort4*)&A2[(size_t)node * 1024 + 768 + lane * 4] = hl;
}

// ---------------- MFMA GRU v5: single 40KB buffer, 4 blocks/CU, setprio, XCD swizzle ------
// Per chunk: stage 40 frags (10/wave) -> __syncthreads (drain) -> 72 MFMA -> __syncthreads.
// Occupancy over pipelining: 16 waves/CU stagger across blocks to hide drain stalls (m114).
__global__ __launch_bounds__(256, 4) void gru_mfma_kernel(const unsigned short* __restrict__ A2,
                                                          const unsigned short* __restrict__ BT2,
                                                          const float* __restrict__ b_ih,
                                                          const float* __restrict__ b_hh,
                                                          float* __restrict__ h, int M) {
    __shared__ unsigned short sm[20480];   // 40 KB
    int tid = threadIdx.x;
    int lane = tid & 63;
    int wid = tid >> 6;          // 0..3
    int wr = wid >> 1, wc = wid & 1;

    // T1: bijective XCD swizzle — 4 bnd-slices of slab g at bids {c, c+8, c+16, c+24}
    int bid = blockIdx.x;   // 0..1563
    int g, by;
    if (bid < 1536) {
        int ch = bid >> 5;
        int rem = bid & 31;
        g = ch * 8 + (rem & 7);
        by = rem >> 3;
    } else {
        int r = bid - 1536;
        g = 384 + (r >> 2);
        by = r & 3;
    }
    int bm = g * 128;
    int bnd = by * 64;

    // 10 staging frags per wave
    unsigned gbase[10];
    bool gA[10], gG2[10];
    #pragma unroll
    for (int ff = 0; ff < 10; ff++) {
        int f = wid * 10 + ff;
        frag_addr(f, bm, bnd, lane, gbase[ff], gA[ff], gG2[ff]);
    }

    f32x4 acc[4][8];
    #pragma unroll
    for (int i = 0; i < 4; i++)
        #pragma unroll
        for (int j = 0; j < 8; j++)
            acc[i][j] = (f32x4){0.f, 0.f, 0.f, 0.f};

#define STAGE(C_)                                                                  \
    { _Pragma("unroll")                                                            \
      for (int ff = 0; ff < 10; ff++) {                                            \
        const unsigned short* gp = (gA[ff] ? A2 : BT2) + gbase[ff]                 \
            + (C_) * 32 + ((gG2[ff] && (C_) >= 8) ? 262144u : 0u);                 \
        gload16(gp, &sm[(wid * 10 + ff) * 512]);                                   \
      } }

#define KBODY(C_, NIOFF_)                                                          \
    {   STAGE(C_)                                                                  \
        __syncthreads();                                                           \
        bf16x8 ah[4], al[4], bh[6], bl[6];                                         \
        _Pragma("unroll")                                                          \
        for (int m = 0; m < 4; m++) {                                              \
            ah[m] = *(const bf16x8*)&sm[(wr * 4 + m) * 512 + lane * 8];            \
            al[m] = *(const bf16x8*)&sm[(8 + wr * 4 + m) * 512 + lane * 8];        \
        }                                                                          \
        _Pragma("unroll")                                                          \
        for (int j = 0; j < 6; j++) {                                              \
            int fb = 16 + (j >> 1) * 4 + wc * 2 + (j & 1);                         \
            bh[j] = *(const bf16x8*)&sm[fb * 512 + lane * 8];                      \
            bl[j] = *(const bf16x8*)&sm[(fb + 12) * 512 + lane * 8];               \
        }                                                                          \
        __builtin_amdgcn_s_setprio(1);                                             \
        _Pragma("unroll")                                                          \
        for (int m = 0; m < 4; m++)                                                \
            _Pragma("unroll")                                                      \
            for (int j = 0; j < 6; j++) {                                          \
                int na = (j < 4) ? j : (NIOFF_) + (j & 1);                         \
                acc[m][na] = __builtin_amdgcn_mfma_f32_16x16x32_bf16(ah[m], bh[j], acc[m][na], 0, 0, 0); \
                acc[m][na] = __builtin_amdgcn_mfma_f32_16x16x32_bf16(al[m], bh[j], acc[m][na], 0, 0, 0); \
                acc[m][na] = __builtin_amdgcn_mfma_f32_16x16x32_bf16(ah[m], bl[j], acc[m][na], 0, 0, 0); \
            }                                                                      \
        __builtin_amdgcn_s_setprio(0);                                             \
        __syncthreads();                                                           \
    }

    KBODY(0, 4)  KBODY(1, 4)  KBODY(2, 4)  KBODY(3, 4)
    KBODY(4, 4)  KBODY(5, 4)  KBODY(6, 4)  KBODY(7, 4)
    KBODY(8, 6)  KBODY(9, 6)  KBODY(10, 6) KBODY(11, 6)
    KBODY(12, 6) KBODY(13, 6) KBODY(14, 6) KBODY(15, 6)
#undef STAGE
#undef KBODY

    // epilogue: C layout col=lane&15, row=(lane>>4)*4+reg; writes fp32 h only
    int rbase = bm + wr * 64 + ((lane >> 4) << 2);
    #pragma unroll
    for (int jj = 0; jj < 2; jj++) {
        int d = bnd + (wc * 2 + jj) * 16 + (lane & 15);
        float cbr = b_ih[d] + b_hh[d];
        float cbz = b_ih[D + d] + b_hh[D + d];
        float bin = b_ih[2 * D + d];
        float bhn = b_hh[2 * D + d];
        #pragma unroll
        for (int m = 0; m < 4; m++) {
            #pragma unroll
            for (int q = 0; q < 4; q++) {
                int row = rbase + m * 16 + q;
                if (row < M) {
                    float r = sigm(acc[m][jj][q] + cbr);
                    float z = sigm(acc[m][2 + jj][q] + cbz);
                    float nn = tanhf(acc[m][4 + jj][q] + bin + r * (acc[m][6 + jj][q] + bhn));
                    float* hp = &h[(size_t)row * D + d];
                    float hv = *hp;
                    *hp = (1.f - z) * nn + z * hv;
                }
            }
        }
    }
}

// ---------------- readout + softmax (float4 hrow) ----------------
__global__ __launch_bounds__(256) void readout_kernel(const float* __restrict__ h,
                                                      const float* __restrict__ w_ro,
                                                      const float* __restrict__ b_ro,
                                                      float* __restrict__ out, int M) {
    __shared__ float ws_[D * K_OUT];
    for (int i = threadIdx.x; i < D * K_OUT; i += 256) ws_[i] = w_ro[i];
    __syncthreads();
    int group = threadIdx.x >> 5;
    int col   = threadIdx.x & 31;
    int node  = blockIdx.x * 8 + group;
    if (node >= M) return;
    float a0 = b_ro[col], a1 = 0.f, a2 = 0.f, a3 = 0.f;
    const float* hrow = &h[(size_t)node * D];
    #pragma unroll 4
    for (int k = 0; k < D; k += 4) {
        float4 hv = *(const float4*)&hrow[k];
        a0 += hv.x * ws_[(k + 0) * K_OUT + col];
        a1 += hv.y * ws_[(k + 1) * K_OUT + col];
        a2 += hv.z * ws_[(k + 2) * K_OUT + col];
        a3 += hv.w * ws_[(k + 3) * K_OUT + col];
    }
    float acc = (a0 + a1) + (a2 + a3);
    float mx = acc;
    #pragma unroll
    for (int off = 16; off > 0; off >>= 1) mx = fmaxf(mx, __shfl_xor(mx, off, 32));
    float e = __expf(acc - mx);
    float s = e;
    #pragma unroll
    for (int off = 16; off > 0; off >>= 1) s += __shfl_xor(s, off, 32);
    out[(size_t)node * K_OUT + col] = e / s;
}

extern "C" void kernel_launch(void* const* d_in, const int* in_sizes, int n_in,
                              void* d_out, int out_size, void* d_ws, size_t ws_size,
                              hipStream_t stream) {
    const float* x      = (const float*)d_in[0];
    const int*   ei     = (const int*)d_in[1];
    const float* ea     = (const float*)d_in[2];
    const float* weight = (const float*)d_in[3];
    const float* w_ih   = (const float*)d_in[4];
    const float* w_hh   = (const float*)d_in[5];
    const float* b_ih   = (const float*)d_in[6];
    const float* b_hh   = (const float*)d_in[7];
    const float* w_ro   = (const float*)d_in[8];
    const float* b_ro   = (const float*)d_in[9];
    float* out = (float*)d_out;

    int N = in_sizes[0];          // 50000
    int E = in_sizes[2];          // 800000
    const int* src = ei;
    const int* dst = ei + E;

    size_t ND = (size_t)N * D;
    float* h = (float*)d_ws;
    unsigned short* A2 = (unsigned short*)(h + ND);                      // NPAD x 1024 bf16
    float* P = (float*)(A2 + (size_t)NPAD * 1024);                       // 4 x 256 x 768
    unsigned short* BT2 = (unsigned short*)(P + (size_t)L_LAYERS * 256 * 768); // 4 x 1024 x 1024
    float* sx = (float*)(BT2 + (size_t)L_LAYERS * 1024 * 1024);
    int* cnt = (int*)(sx + N);
    int* rowptr = cnt + (N + 1);
    int* cursor = rowptr + (N + 1);
    int* esrc = cursor + (N + 1);
    float* eval = (float*)(esrc + E);

    // ---- CSR build ----
    hipMemsetAsync(cnt, 0, (N + 1) * sizeof(int), stream);
    hist_kernel<<<1024, 256, 0, stream>>>(dst, cnt, E);
    scan_kernel<<<1, 1024, 0, stream>>>(cnt, rowptr, cursor, N);
    reorder_kernel<<<1024, 256, 0, stream>>>(src, dst, ea, cursor, esrc, eval, E);

    // ---- weight precompute ----
    prep_wih_kernel<<<dim3(4, 12, 4), 256, 0, stream>>>(weight, w_ih, P);
    pack_bt2_kernel<<<16384, 256, 0, stream>>>(P, w_hh, BT2);

    // ---- layer 0 (rank-2) ----
    sgather_kernel<<<(N + 255) / 256, 256, 0, stream>>>(x, rowptr, esrc, eval, sx, N);
    layer0_kernel<<<(N + 3) / 4, 256, 0, stream>>>(x, sx, P, w_hh, b_ih, b_hh, h, N);

    // ---- layers 1..3 ----
    int nb = (NPAD / 128) * 4;    // 1564, 1D swizzled grid
    int gather_blocks = (N * 64 + 255) / 256;
    for (int l = 1; l < L_LAYERS; l++) {
        gather_bf_kernel<<<gather_blocks, 256, 0, stream>>>(h, rowptr, esrc, eval, A2, N);
        gru_mfma_kernel<<<nb, 256, 0, stream>>>(A2, BT2 + (size_t)l * 1024 * 1024,
                                                b_ih, b_hh, h, N);
    }
    readout_kernel<<<(N + 7) / 8, 256, 0, stream>>>(h, w_ro, b_ro, out, N);
}

// Round 11
// 1436.910 us; speedup vs baseline: 2.6154x; 2.6154x over previous
//
#include <hip/hip_runtime.h>

#define D 256
#define K_OUT 32
#define L_LAYERS 4
#define NPAD 50048

typedef __attribute__((ext_vector_type(8))) short bf16x8;
typedef __attribute__((ext_vector_type(4))) float f32x4;
typedef __attribute__((address_space(3))) unsigned int lds_u32;
typedef const __attribute__((address_space(1))) unsigned int glb_u32;

__device__ __forceinline__ float sigm(float v) { return 1.f / (1.f + __expf(-v)); }
__device__ __forceinline__ unsigned short f2bf(float f) {
    unsigned u = __float_as_uint(f);
    u = u + 0x7fffu + ((u >> 16) & 1u);
    return (unsigned short)(u >> 16);
}
__device__ __forceinline__ float bf2f(unsigned short s) {
    return __uint_as_float(((unsigned)s) << 16);
}
__device__ __forceinline__ void gload16(const unsigned short* g, unsigned short* l) {
    __builtin_amdgcn_global_load_lds((glb_u32*)g, (lds_u32*)l, 16, 0, 0);
}

// frag id f -> A2/BT2 offset (ushort units): 0-7 A_hi, 8-15 A_lo, 16-27 B_hi, 28-39 B_lo
__device__ __forceinline__ void frag_addr(int f, int bm, int bnd, int lane,
                                          unsigned& off, bool& isA, bool& isG2) {
    if (f < 8) {
        off = (unsigned)(bm + f * 16 + (lane & 15)) * 1024u + ((lane >> 4) << 3);
        isA = true; isG2 = false;
    } else if (f < 16) {
        off = (unsigned)(bm + (f - 8) * 16 + (lane & 15)) * 1024u + 512u + ((lane >> 4) << 3);
        isA = true; isG2 = false;
    } else if (f < 28) {
        int q = f - 16; int gs = q >> 2; int df = q & 3;
        off = (unsigned)(gs * 256 + bnd + df * 16 + (lane & 15)) * 1024u + ((lane >> 4) << 3);
        isA = false; isG2 = (gs == 2);
    } else {
        int q = f - 28; int gs = q >> 2; int df = q & 3;
        off = (unsigned)(gs * 256 + bnd + df * 16 + (lane & 15)) * 1024u + 512u + ((lane >> 4) << 3);
        isA = false; isG2 = (gs == 2);
    }
}

// ---------------- CSR build ----------------
__global__ __launch_bounds__(256) void hist_kernel(const int* __restrict__ dst,
                                                   int* __restrict__ cnt, int E) {
    int idx = blockIdx.x * blockDim.x + threadIdx.x;
    for (int e = idx; e < E; e += gridDim.x * blockDim.x)
        atomicAdd(&cnt[dst[e]], 1);
}

__global__ __launch_bounds__(1024) void scan_kernel(const int* __restrict__ cnt,
                                                    int* __restrict__ rowptr,
                                                    int* __restrict__ cursor, int n) {
    __shared__ int sdata[1024];
    int t = threadIdx.x;
    int chunk = (n + 1023) / 1024;
    int start = t * chunk;
    int end = start + chunk; if (end > n) end = n;
    int s = 0;
    for (int i = start; i < end; i++) s += cnt[i];
    sdata[t] = s;
    __syncthreads();
    for (int off = 1; off < 1024; off <<= 1) {
        int v = (t >= off) ? sdata[t - off] : 0;
        __syncthreads();
        sdata[t] += v;
        __syncthreads();
    }
    int base = sdata[t] - s;
    for (int i = start; i < end; i++) {
        rowptr[i] = base;
        cursor[i] = base;
        base += cnt[i];
    }
    if (end == n && start <= n) rowptr[n] = base;
}

__global__ __launch_bounds__(256) void reorder_kernel(const int* __restrict__ src,
                                                      const int* __restrict__ dst,
                                                      const float* __restrict__ ea,
                                                      int* __restrict__ cursor,
                                                      int* __restrict__ esrc,
                                                      float* __restrict__ eval, int E) {
    int idx = blockIdx.x * blockDim.x + threadIdx.x;
    for (int e = idx; e < E; e += gridDim.x * blockDim.x) {
        int slot = atomicAdd(&cursor[dst[e]], 1);
        esrc[slot] = src[e];
        eval[slot] = ea[e];
    }
}

// ---------------- P[l][k][c3] = (weight[l] @ w_ih^T)[k][c3], 256x768 per layer ----------------
__global__ __launch_bounds__(256) void prep_wih_kernel(const float* __restrict__ weight,
                                                       const float* __restrict__ w_ih,
                                                       float* __restrict__ P) {
    int l = blockIdx.z;
    const float* A = weight + (size_t)l * D * D;
    float* Cdst = P + (size_t)l * 256 * 768;
    __shared__ float As[32][64 + 4];
    __shared__ float Bs[32][64 + 4];
    int tid = threadIdx.x;
    int tx = tid & 15, ty = tid >> 4;
    int bk = blockIdx.x * 64;
    int bn = blockIdx.y * 64;
    float acc[4][4] = {};
    for (int jb = 0; jb < D; jb += 32) {
        #pragma unroll
        for (int i = 0; i < 2; i++) {
            int lin = tid + i * 256;
            int row = lin >> 3;
            int c4 = (lin & 7) << 2;
            float4 v = *(const float4*)&A[(size_t)(bk + row) * D + jb + c4];
            As[c4+0][row]=v.x; As[c4+1][row]=v.y; As[c4+2][row]=v.z; As[c4+3][row]=v.w;
            float4 w = *(const float4*)&w_ih[(size_t)(bn + row) * D + jb + c4];
            Bs[c4+0][row]=w.x; Bs[c4+1][row]=w.y; Bs[c4+2][row]=w.z; Bs[c4+3][row]=w.w;
        }
        __syncthreads();
        #pragma unroll
        for (int jj = 0; jj < 32; jj++) {
            float a[4], b[4];
            *(float4*)a = *(const float4*)&As[jj][ty*4];
            *(float4*)b = *(const float4*)&Bs[jj][tx*4];
            #pragma unroll
            for (int i = 0; i < 4; i++)
                #pragma unroll
                for (int j = 0; j < 4; j++)
                    acc[i][j] += a[i] * b[j];
        }
        __syncthreads();
    }
    #pragma unroll
    for (int i = 0; i < 4; i++)
        *(float4*)&Cdst[(size_t)(bk + ty*4 + i) * 768 + bn + tx*4] =
            make_float4(acc[i][0], acc[i][1], acc[i][2], acc[i][3]);
}

// ---------------- BT2[l][c][k2] bf16: c=g*256+d (g: r,z,ni,nh), k2<512 hi, >=512 lo ----------------
__global__ __launch_bounds__(256) void pack_bt2_kernel(const float* __restrict__ P,
                                                       const float* __restrict__ w_hh,
                                                       unsigned short* __restrict__ BT2) {
    long long idx = (long long)blockIdx.x * 256 + threadIdx.x;   // 4M total
    int l = (int)(idx >> 20);
    int rem = (int)(idx & 1048575);
    int c = rem >> 10;
    int k2 = rem & 1023;
    int g = c >> 8, d = c & 255;
    int k = k2 & 511;
    float val;
    if (k < 256) {
        val = (g == 0) ? P[(size_t)l * 196608 + (size_t)k * 768 + d]
            : (g == 1) ? P[(size_t)l * 196608 + (size_t)k * 768 + 256 + d]
            : (g == 2) ? P[(size_t)l * 196608 + (size_t)k * 768 + 512 + d]
            : 0.f;
    } else {
        int kk = k - 256;
        val = (g == 0) ? w_hh[(size_t)d * D + kk]
            : (g == 1) ? w_hh[(size_t)(256 + d) * D + kk]
            : (g == 3) ? w_hh[(size_t)(512 + d) * D + kk]
            : 0.f;
    }
    unsigned short hi = f2bf(val);
    BT2[idx] = (k2 < 512) ? hi : f2bf(val - bf2f(hi));
}

// ---------------- scalar gather: sx[n] = sum ea * x[src] ----------------
__global__ __launch_bounds__(256) void sgather_kernel(const float* __restrict__ x,
                                                      const int* __restrict__ rowptr,
                                                      const int* __restrict__ esrc,
                                                      const float* __restrict__ eval,
                                                      float* __restrict__ sx, int n) {
    int node = blockIdx.x * blockDim.x + threadIdx.x;
    if (node >= n) return;
    float s = 0.f;
    int end = rowptr[node + 1];
    for (int e = rowptr[node]; e < end; e++) s += eval[e] * x[esrc[e]];
    sx[node] = s;
}

// ---------------- layer 0: rank-2 + GRU epilogue, writes h ----------------
__global__ __launch_bounds__(256) void layer0_kernel(const float* __restrict__ x,
                                                     const float* __restrict__ sx,
                                                     const float* __restrict__ P0,
                                                     const float* __restrict__ w_hh,
                                                     const float* __restrict__ b_ih,
                                                     const float* __restrict__ b_hh,
                                                     float* __restrict__ hout, int M) {
    int node = blockIdx.x * 4 + (threadIdx.x >> 6);
    if (node >= M) return;
    int d0 = (threadIdx.x & 63) * 4;
    float sxn = sx[node], xn = x[node];
    float4 r0 = *(const float4*)&P0[d0];
    float4 z0 = *(const float4*)&P0[256 + d0];
    float4 n0 = *(const float4*)&P0[512 + d0];
    float r1[4], z1[4], n1[4];
    #pragma unroll
    for (int j = 0; j < 4; j++) {
        r1[j] = w_hh[(size_t)(d0 + j) * D];
        z1[j] = w_hh[(size_t)(256 + d0 + j) * D];
        n1[j] = w_hh[(size_t)(512 + d0 + j) * D];
    }
    float4 bir = *(const float4*)&b_ih[d0];
    float4 biz = *(const float4*)&b_ih[256 + d0];
    float4 bin = *(const float4*)&b_ih[512 + d0];
    float4 bhr = *(const float4*)&b_hh[d0];
    float4 bhz = *(const float4*)&b_hh[256 + d0];
    float4 bhn = *(const float4*)&b_hh[512 + d0];
    float rr[4] = {sxn*r0.x + xn*r1[0] + bir.x + bhr.x, sxn*r0.y + xn*r1[1] + bir.y + bhr.y,
                   sxn*r0.z + xn*r1[2] + bir.z + bhr.z, sxn*r0.w + xn*r1[3] + bir.w + bhr.w};
    float zz[4] = {sxn*z0.x + xn*z1[0] + biz.x + bhz.x, sxn*z0.y + xn*z1[1] + biz.y + bhz.y,
                   sxn*z0.z + xn*z1[2] + biz.z + bhz.z, sxn*z0.w + xn*z1[3] + biz.w + bhz.w};
    float ni[4] = {sxn*n0.x + bin.x, sxn*n0.y + bin.y, sxn*n0.z + bin.z, sxn*n0.w + bin.w};
    float nh[4] = {xn*n1[0] + bhn.x, xn*n1[1] + bhn.y, xn*n1[2] + bhn.z, xn*n1[3] + bhn.w};
    float o[4];
    #pragma unroll
    for (int j = 0; j < 4; j++) {
        float r = sigm(rr[j]);
        float z = sigm(zz[j]);
        float nn = tanhf(ni[j] + r * nh[j]);
        float hp = (d0 + j == 0) ? xn : 0.f;
        o[j] = (1.f - z) * nn + z * hp;
    }
    *(float4*)&hout[(size_t)node * D + d0] = make_float4(o[0], o[1], o[2], o[3]);
}

// ---------------- gather + fused h2bf (runs after gru completes; kernel boundary) ----------
__global__ __launch_bounds__(256) void gather_bf_kernel(const float* __restrict__ h,
                                                        const int* __restrict__ rowptr,
                                                        const int* __restrict__ esrc,
                                                        const float* __restrict__ eval,
                                                        unsigned short* __restrict__ A2, int n) {
    int node = (blockIdx.x * 256 + threadIdx.x) >> 6;
    int lane = threadIdx.x & 63;
    if (node >= n) return;
    int beg = rowptr[node], end = rowptr[node + 1];
    float4 acc0 = make_float4(0.f, 0.f, 0.f, 0.f);
    float4 acc1 = make_float4(0.f, 0.f, 0.f, 0.f);
    int e = beg;
    for (; e + 1 < end; e += 2) {
        int s0 = esrc[e], s1 = esrc[e + 1];
        float a0 = eval[e], a1 = eval[e + 1];
        float4 v0 = *(const float4*)&h[(size_t)s0 * D + lane * 4];
        float4 v1 = *(const float4*)&h[(size_t)s1 * D + lane * 4];
        acc0.x += a0 * v0.x; acc0.y += a0 * v0.y; acc0.z += a0 * v0.z; acc0.w += a0 * v0.w;
        acc1.x += a1 * v1.x; acc1.y += a1 * v1.y; acc1.z += a1 * v1.z; acc1.w += a1 * v1.w;
    }
    if (e < end) {
        int s0 = esrc[e];
        float a0 = eval[e];
        float4 v0 = *(const float4*)&h[(size_t)s0 * D + lane * 4];
        acc0.x += a0 * v0.x; acc0.y += a0 * v0.y; acc0.z += a0 * v0.z; acc0.w += a0 * v0.w;
    }
    float4 acc = make_float4(acc0.x + acc1.x, acc0.y + acc1.y, acc0.z + acc1.z, acc0.w + acc1.w);
    ushort4 hi = make_ushort4(f2bf(acc.x), f2bf(acc.y), f2bf(acc.z), f2bf(acc.w));
    ushort4 lo = make_ushort4(f2bf(acc.x - bf2f(hi.x)), f2bf(acc.y - bf2f(hi.y)),
                              f2bf(acc.z - bf2f(hi.z)), f2bf(acc.w - bf2f(hi.w)));
    *(ushort4*)&A2[(size_t)node * 1024 + lane * 4] = hi;
    *(ushort4*)&A2[(size_t)node * 1024 + 512 + lane * 4] = lo;
    float4 hv = *(const float4*)&h[(size_t)node * D + lane * 4];
    ushort4 hh = make_ushort4(f2bf(hv.x), f2bf(hv.y), f2bf(hv.z), f2bf(hv.w));
    ushort4 hl = make_ushort4(f2bf(hv.x - bf2f(hh.x)), f2bf(hv.y - bf2f(hh.y)),
                              f2bf(hv.z - bf2f(hh.z)), f2bf(hv.w - bf2f(hh.w)));
    *(ushort4*)&A2[(size_t)node * 1024 + 256 + lane * 4] = hh;
    *(ushort4*)&A2[(size_t)node * 1024 + 768 + lane * 4] = hl;
}

// ---------------- MFMA GRU v6 = R9's v4 (proven 195us) + T5 setprio ----------------
// launch_bounds (256,2): acc 128 + operands needs ~250 regs; (256,4) spills catastrophically (R10).
__global__ __launch_bounds__(256, 2) void gru_mfma_kernel(const unsigned short* __restrict__ A2,
                                                          const unsigned short* __restrict__ BT2,
                                                          const float* __restrict__ b_ih,
                                                          const float* __restrict__ b_hh,
                                                          float* __restrict__ h, int M) {
    __shared__ unsigned short sm[2][20480];   // 80 KB
    int tid = threadIdx.x;
    int lane = tid & 63;
    int wid = tid >> 6;
    int wr = wid >> 1, wc = wid & 1;

    // T1: bijective XCD swizzle — the 4 bnd-slices of slab g get bids {c, c+8, c+16, c+24}
    int bid = blockIdx.x;   // 0..1563
    int g, by;
    if (bid < 1536) {
        int ch = bid >> 5;
        int rem = bid & 31;
        g = ch * 8 + (rem & 7);
        by = rem >> 3;
    } else {
        int r = bid - 1536;
        g = 384 + (r >> 2);
        by = r & 3;
    }
    int bm = g * 128;
    int bnd = by * 64;

    // per-wave staging tables: 5 H0 frags + 5 H1 frags
    unsigned g0off[5], g1off[5];
    int slot0[5], slot1[5];
    bool g0A[5], g0G2[5], g1A[5], g1G2[5];
    #pragma unroll
    for (int i = 0; i < 5; i++) {
        int idx = wid * 5 + i;
        int f0 = (idx < 8) ? idx : idx + 8;        // H0: 0-7 (A_hi), 16-27 (B_hi)
        int f1 = (idx < 8) ? idx + 8 : idx + 20;   // H1: 8-15 (A_lo), 28-39 (B_lo)
        frag_addr(f0, bm, bnd, lane, g0off[i], g0A[i], g0G2[i]);
        frag_addr(f1, bm, bnd, lane, g1off[i], g1A[i], g1G2[i]);
        slot0[i] = f0; slot1[i] = f1;
    }

    f32x4 acc[4][8];
    #pragma unroll
    for (int i = 0; i < 4; i++)
        #pragma unroll
        for (int j = 0; j < 8; j++)
            acc[i][j] = (f32x4){0.f, 0.f, 0.f, 0.f};

    bf16x8 ah[4], al[4], bh[6], bl[6];

#define STAGE_H0(C_, B_)                                                           \
    { _Pragma("unroll")                                                            \
      for (int i = 0; i < 5; i++) {                                                \
        const unsigned short* gp = (g0A[i] ? A2 : BT2) + g0off[i]                  \
            + (C_) * 32 + ((g0G2[i] && (C_) >= 8) ? 262144u : 0u);                 \
        gload16(gp, &sm[B_][slot0[i] * 512]);                                      \
      } }
#define STAGE_H1(C_, B_)                                                           \
    { _Pragma("unroll")                                                            \
      for (int i = 0; i < 5; i++) {                                                \
        const unsigned short* gp = (g1A[i] ? A2 : BT2) + g1off[i]                  \
            + (C_) * 32 + ((g1G2[i] && (C_) >= 8) ? 262144u : 0u);                 \
        gload16(gp, &sm[B_][slot1[i] * 512]);                                      \
      } }

#define KBODY(C_, NIOFF_)                                                          \
    {   int cur = (C_) & 1;                                                        \
        asm volatile("s_waitcnt vmcnt(5)" ::: "memory");                           \
        __builtin_amdgcn_sched_barrier(0);                                         \
        __builtin_amdgcn_s_barrier();                                              \
        if ((C_) < 15) { STAGE_H0((C_) + 1, cur ^ 1); STAGE_H1((C_) + 1, cur ^ 1); } \
        _Pragma("unroll")                                                          \
        for (int m = 0; m < 4; m++)                                                \
            ah[m] = *(const bf16x8*)&sm[cur][(wr * 4 + m) * 512 + lane * 8];       \
        _Pragma("unroll")                                                          \
        for (int j = 0; j < 6; j++) {                                              \
            int fb = 16 + (j >> 1) * 4 + wc * 2 + (j & 1);                         \
            bh[j] = *(const bf16x8*)&sm[cur][fb * 512 + lane * 8];                 \
        }                                                                          \
        __builtin_amdgcn_s_setprio(1);                                             \
        _Pragma("unroll")                                                          \
        for (int m = 0; m < 4; m++)                                                \
            _Pragma("unroll")                                                      \
            for (int j = 0; j < 6; j++) {                                          \
                int na = (j < 4) ? j : (NIOFF_) + (j & 1);                         \
                acc[m][na] = __builtin_amdgcn_mfma_f32_16x16x32_bf16(ah[m], bh[j], acc[m][na], 0, 0, 0); \
            }                                                                      \
        __builtin_amdgcn_s_setprio(0);                                             \
        if ((C_) < 15) { asm volatile("s_waitcnt vmcnt(10)" ::: "memory"); }       \
        else           { asm volatile("s_waitcnt vmcnt(0)"  ::: "memory"); }       \
        __builtin_amdgcn_sched_barrier(0);                                         \
        __builtin_amdgcn_s_barrier();                                              \
        _Pragma("unroll")                                                          \
        for (int m = 0; m < 4; m++)                                                \
            al[m] = *(const bf16x8*)&sm[cur][(8 + wr * 4 + m) * 512 + lane * 8];   \
        _Pragma("unroll")                                                          \
        for (int j = 0; j < 6; j++) {                                              \
            int fb = 16 + (j >> 1) * 4 + wc * 2 + (j & 1);                         \
            bl[j] = *(const bf16x8*)&sm[cur][(fb + 12) * 512 + lane * 8];          \
        }                                                                          \
        __builtin_amdgcn_s_setprio(1);                                             \
        _Pragma("unroll")                                                          \
        for (int m = 0; m < 4; m++)                                                \
            _Pragma("unroll")                                                      \
            for (int j = 0; j < 6; j++) {                                          \
                int na = (j < 4) ? j : (NIOFF_) + (j & 1);                         \
                acc[m][na] = __builtin_amdgcn_mfma_f32_16x16x32_bf16(al[m], bh[j], acc[m][na], 0, 0, 0); \
                acc[m][na] = __builtin_amdgcn_mfma_f32_16x16x32_bf16(ah[m], bl[j], acc[m][na], 0, 0, 0); \
            }                                                                      \
        __builtin_amdgcn_s_setprio(0);                                             \
    }

    STAGE_H0(0, 0); STAGE_H1(0, 0);
    KBODY(0, 4)  KBODY(1, 4)  KBODY(2, 4)  KBODY(3, 4)
    KBODY(4, 4)  KBODY(5, 4)  KBODY(6, 4)  KBODY(7, 4)
    KBODY(8, 6)  KBODY(9, 6)  KBODY(10, 6) KBODY(11, 6)
    KBODY(12, 6) KBODY(13, 6) KBODY(14, 6) KBODY(15, 6)
#undef STAGE_H0
#undef STAGE_H1
#undef KBODY

    // epilogue: C layout col=lane&15, row=(lane>>4)*4+reg; writes fp32 h only
    int rbase = bm + wr * 64 + ((lane >> 4) << 2);
    #pragma unroll
    for (int jj = 0; jj < 2; jj++) {
        int d = bnd + (wc * 2 + jj) * 16 + (lane & 15);
        float cbr = b_ih[d] + b_hh[d];
        float cbz = b_ih[D + d] + b_hh[D + d];
        float bin = b_ih[2 * D + d];
        float bhn = b_hh[2 * D + d];
        #pragma unroll
        for (int m = 0; m < 4; m++) {
            #pragma unroll
            for (int q = 0; q < 4; q++) {
                int row = rbase + m * 16 + q;
                if (row < M) {
                    float r = sigm(acc[m][jj][q] + cbr);
                    float z = sigm(acc[m][2 + jj][q] + cbz);
                    float nn = tanhf(acc[m][4 + jj][q] + bin + r * (acc[m][6 + jj][q] + bhn));
                    float* hp = &h[(size_t)row * D + d];
                    float hv = *hp;
                    *hp = (1.f - z) * nn + z * hv;
                }
            }
        }
    }
}

// ---------------- readout + softmax (float4 hrow) ----------------
__global__ __launch_bounds__(256) void readout_kernel(const float* __restrict__ h,
                                                      const float* __restrict__ w_ro,
                                                      const float* __restrict__ b_ro,
                                                      float* __restrict__ out, int M) {
    __shared__ float ws_[D * K_OUT];
    for (int i = threadIdx.x; i < D * K_OUT; i += 256) ws_[i] = w_ro[i];
    __syncthreads();
    int group = threadIdx.x >> 5;
    int col   = threadIdx.x & 31;
    int node  = blockIdx.x * 8 + group;
    if (node >= M) return;
    float a0 = b_ro[col], a1 = 0.f, a2 = 0.f, a3 = 0.f;
    const float* hrow = &h[(size_t)node * D];
    #pragma unroll 4
    for (int k = 0; k < D; k += 4) {
        float4 hv = *(const float4*)&hrow[k];
        a0 += hv.x * ws_[(k + 0) * K_OUT + col];
        a1 += hv.y * ws_[(k + 1) * K_OUT + col];
        a2 += hv.z * ws_[(k + 2) * K_OUT + col];
        a3 += hv.w * ws_[(k + 3) * K_OUT + col];
    }
    float acc = (a0 + a1) + (a2 + a3);
    float mx = acc;
    #pragma unroll
    for (int off = 16; off > 0; off >>= 1) mx = fmaxf(mx, __shfl_xor(mx, off, 32));
    float e = __expf(acc - mx);
    float s = e;
    #pragma unroll
    for (int off = 16; off > 0; off >>= 1) s += __shfl_xor(s, off, 32);
    out[(size_t)node * K_OUT + col] = e / s;
}

extern "C" void kernel_launch(void* const* d_in, const int* in_sizes, int n_in,
                              void* d_out, int out_size, void* d_ws, size_t ws_size,
                              hipStream_t stream) {
    const float* x      = (const float*)d_in[0];
    const int*   ei     = (const int*)d_in[1];
    const float* ea     = (const float*)d_in[2];
    const float* weight = (const float*)d_in[3];
    const float* w_ih   = (const float*)d_in[4];
    const float* w_hh   = (const float*)d_in[5];
    const float* b_ih   = (const float*)d_in[6];
    const float* b_hh   = (const float*)d_in[7];
    const float* w_ro   = (const float*)d_in[8];
    const float* b_ro   = (const float*)d_in[9];
    float* out = (float*)d_out;

    int N = in_sizes[0];          // 50000
    int E = in_sizes[2];          // 800000
    const int* src = ei;
    const int* dst = ei + E;

    size_t ND = (size_t)N * D;
    float* h = (float*)d_ws;
    unsigned short* A2 = (unsigned short*)(h + ND);                      // NPAD x 1024 bf16
    float* P = (float*)(A2 + (size_t)NPAD * 1024);                       // 4 x 256 x 768
    unsigned short* BT2 = (unsigned short*)(P + (size_t)L_LAYERS * 256 * 768); // 4 x 1024 x 1024
    float* sx = (float*)(BT2 + (size_t)L_LAYERS * 1024 * 1024);
    int* cnt = (int*)(sx + N);
    int* rowptr = cnt + (N + 1);
    int* cursor = rowptr + (N + 1);
    int* esrc = cursor + (N + 1);
    float* eval = (float*)(esrc + E);

    // ---- CSR build ----
    hipMemsetAsync(cnt, 0, (N + 1) * sizeof(int), stream);
    hist_kernel<<<1024, 256, 0, stream>>>(dst, cnt, E);
    scan_kernel<<<1, 1024, 0, stream>>>(cnt, rowptr, cursor, N);
    reorder_kernel<<<1024, 256, 0, stream>>>(src, dst, ea, cursor, esrc, eval, E);

    // ---- weight precompute ----
    prep_wih_kernel<<<dim3(4, 12, 4), 256, 0, stream>>>(weight, w_ih, P);
    pack_bt2_kernel<<<16384, 256, 0, stream>>>(P, w_hh, BT2);

    // ---- layer 0 (rank-2) ----
    sgather_kernel<<<(N + 255) / 256, 256, 0, stream>>>(x, rowptr, esrc, eval, sx, N);
    layer0_kernel<<<(N + 3) / 4, 256, 0, stream>>>(x, sx, P, w_hh, b_ih, b_hh, h, N);

    // ---- layers 1..3 ----
    int nb = (NPAD / 128) * 4;    // 1564, 1D swizzled grid
    int gather_blocks = (N * 64 + 255) / 256;
    for (int l = 1; l < L_LAYERS; l++) {
        gather_bf_kernel<<<gather_blocks, 256, 0, stream>>>(h, rowptr, esrc, eval, A2, N);
        gru_mfma_kernel<<<nb, 256, 0, stream>>>(A2, BT2 + (size_t)l * 1024 * 1024,
                                                b_ih, b_hh, h, N);
    }
    readout_kernel<<<(N + 7) / 8, 256, 0, stream>>>(h, w_ro, b_ro, out, N);
}

// Round 12
// 1425.209 us; speedup vs baseline: 2.6368x; 1.0082x over previous
//
#include <hip/hip_runtime.h>

#define D 256
#define K_OUT 32
#define L_LAYERS 4
#define NPAD 50048

typedef __attribute__((ext_vector_type(8))) short bf16x8;
typedef __attribute__((ext_vector_type(4))) float f32x4;
typedef __attribute__((address_space(3))) unsigned int lds_u32;
typedef const __attribute__((address_space(1))) unsigned int glb_u32;

__device__ __forceinline__ float sigm(float v) { return 1.f / (1.f + __expf(-v)); }
__device__ __forceinline__ unsigned short f2bf(float f) {
    unsigned u = __float_as_uint(f);
    u = u + 0x7fffu + ((u >> 16) & 1u);
    return (unsigned short)(u >> 16);
}
__device__ __forceinline__ float bf2f(unsigned short s) {
    return __uint_as_float(((unsigned)s) << 16);
}
__device__ __forceinline__ void gload16(const unsigned short* g, unsigned short* l) {
    __builtin_amdgcn_global_load_lds((glb_u32*)g, (lds_u32*)l, 16, 0, 0);
}

// frag id f -> A2/BT2 offset (ushort units): 0-7 A_hi, 8-15 A_lo, 16-27 B_hi, 28-39 B_lo
__device__ __forceinline__ void frag_addr(int f, int bm, int bnd, int lane,
                                          unsigned& off, bool& isA, bool& isG2) {
    if (f < 8) {
        off = (unsigned)(bm + f * 16 + (lane & 15)) * 1024u + ((lane >> 4) << 3);
        isA = true; isG2 = false;
    } else if (f < 16) {
        off = (unsigned)(bm + (f - 8) * 16 + (lane & 15)) * 1024u + 512u + ((lane >> 4) << 3);
        isA = true; isG2 = false;
    } else if (f < 28) {
        int q = f - 16; int gs = q >> 2; int df = q & 3;
        off = (unsigned)(gs * 256 + bnd + df * 16 + (lane & 15)) * 1024u + ((lane >> 4) << 3);
        isA = false; isG2 = (gs == 2);
    } else {
        int q = f - 28; int gs = q >> 2; int df = q & 3;
        off = (unsigned)(gs * 256 + bnd + df * 16 + (lane & 15)) * 1024u + 512u + ((lane >> 4) << 3);
        isA = false; isG2 = (gs == 2);
    }
}

// ---------------- CSR build ----------------
__global__ __launch_bounds__(256) void hist_kernel(const int* __restrict__ dst,
                                                   int* __restrict__ cnt, int E) {
    int idx = blockIdx.x * blockDim.x + threadIdx.x;
    for (int e = idx; e < E; e += gridDim.x * blockDim.x)
        atomicAdd(&cnt[dst[e]], 1);
}

__global__ __launch_bounds__(1024) void scan_kernel(const int* __restrict__ cnt,
                                                    int* __restrict__ rowptr,
                                                    int* __restrict__ cursor, int n) {
    __shared__ int sdata[1024];
    int t = threadIdx.x;
    int chunk = (n + 1023) / 1024;
    int start = t * chunk;
    int end = start + chunk; if (end > n) end = n;
    int s = 0;
    for (int i = start; i < end; i++) s += cnt[i];
    sdata[t] = s;
    __syncthreads();
    for (int off = 1; off < 1024; off <<= 1) {
        int v = (t >= off) ? sdata[t - off] : 0;
        __syncthreads();
        sdata[t] += v;
        __syncthreads();
    }
    int base = sdata[t] - s;
    for (int i = start; i < end; i++) {
        rowptr[i] = base;
        cursor[i] = base;
        base += cnt[i];
    }
    if (end == n && start <= n) rowptr[n] = base;
}

__global__ __launch_bounds__(256) void reorder_kernel(const int* __restrict__ src,
                                                      const int* __restrict__ dst,
                                                      const float* __restrict__ ea,
                                                      int* __restrict__ cursor,
                                                      int* __restrict__ esrc,
                                                      float* __restrict__ eval, int E) {
    int idx = blockIdx.x * blockDim.x + threadIdx.x;
    for (int e = idx; e < E; e += gridDim.x * blockDim.x) {
        int slot = atomicAdd(&cursor[dst[e]], 1);
        esrc[slot] = src[e];
        eval[slot] = ea[e];
    }
}

// ---------------- P[l][k][c3] = (weight[l] @ w_ih^T)[k][c3], 256x768 per layer ----------------
__global__ __launch_bounds__(256) void prep_wih_kernel(const float* __restrict__ weight,
                                                       const float* __restrict__ w_ih,
                                                       float* __restrict__ P) {
    int l = blockIdx.z;
    const float* A = weight + (size_t)l * D * D;
    float* Cdst = P + (size_t)l * 256 * 768;
    __shared__ float As[32][64 + 4];
    __shared__ float Bs[32][64 + 4];
    int tid = threadIdx.x;
    int tx = tid & 15, ty = tid >> 4;
    int bk = blockIdx.x * 64;
    int bn = blockIdx.y * 64;
    float acc[4][4] = {};
    for (int jb = 0; jb < D; jb += 32) {
        #pragma unroll
        for (int i = 0; i < 2; i++) {
            int lin = tid + i * 256;
            int row = lin >> 3;
            int c4 = (lin & 7) << 2;
            float4 v = *(const float4*)&A[(size_t)(bk + row) * D + jb + c4];
            As[c4+0][row]=v.x; As[c4+1][row]=v.y; As[c4+2][row]=v.z; As[c4+3][row]=v.w;
            float4 w = *(const float4*)&w_ih[(size_t)(bn + row) * D + jb + c4];
            Bs[c4+0][row]=w.x; Bs[c4+1][row]=w.y; Bs[c4+2][row]=w.z; Bs[c4+3][row]=w.w;
        }
        __syncthreads();
        #pragma unroll
        for (int jj = 0; jj < 32; jj++) {
            float a[4], b[4];
            *(float4*)a = *(const float4*)&As[jj][ty*4];
            *(float4*)b = *(const float4*)&Bs[jj][tx*4];
            #pragma unroll
            for (int i = 0; i < 4; i++)
                #pragma unroll
                for (int j = 0; j < 4; j++)
                    acc[i][j] += a[i] * b[j];
        }
        __syncthreads();
    }
    #pragma unroll
    for (int i = 0; i < 4; i++)
        *(float4*)&Cdst[(size_t)(bk + ty*4 + i) * 768 + bn + tx*4] =
            make_float4(acc[i][0], acc[i][1], acc[i][2], acc[i][3]);
}

// ---------------- BT2[l][c][k2] bf16: c=g*256+d (g: r,z,ni,nh), k2<512 hi, >=512 lo ----------------
__global__ __launch_bounds__(256) void pack_bt2_kernel(const float* __restrict__ P,
                                                       const float* __restrict__ w_hh,
                                                       unsigned short* __restrict__ BT2) {
    long long idx = (long long)blockIdx.x * 256 + threadIdx.x;   // 4M total
    int l = (int)(idx >> 20);
    int rem = (int)(idx & 1048575);
    int c = rem >> 10;
    int k2 = rem & 1023;
    int g = c >> 8, d = c & 255;
    int k = k2 & 511;
    float val;
    if (k < 256) {
        val = (g == 0) ? P[(size_t)l * 196608 + (size_t)k * 768 + d]
            : (g == 1) ? P[(size_t)l * 196608 + (size_t)k * 768 + 256 + d]
            : (g == 2) ? P[(size_t)l * 196608 + (size_t)k * 768 + 512 + d]
            : 0.f;
    } else {
        int kk = k - 256;
        val = (g == 0) ? w_hh[(size_t)d * D + kk]
            : (g == 1) ? w_hh[(size_t)(256 + d) * D + kk]
            : (g == 3) ? w_hh[(size_t)(512 + d) * D + kk]
            : 0.f;
    }
    unsigned short hi = f2bf(val);
    BT2[idx] = (k2 < 512) ? hi : f2bf(val - bf2f(hi));
}

// ---------------- scalar gather: sx[n] = sum ea * x[src] ----------------
__global__ __launch_bounds__(256) void sgather_kernel(const float* __restrict__ x,
                                                      const int* __restrict__ rowptr,
                                                      const int* __restrict__ esrc,
                                                      const float* __restrict__ eval,
                                                      float* __restrict__ sx, int n) {
    int node = blockIdx.x * blockDim.x + threadIdx.x;
    if (node >= n) return;
    float s = 0.f;
    int end = rowptr[node + 1];
    for (int e = rowptr[node]; e < end; e++) s += eval[e] * x[esrc[e]];
    sx[node] = s;
}

// ---------------- layer 0: rank-2 + GRU epilogue, writes h ----------------
__global__ __launch_bounds__(256) void layer0_kernel(const float* __restrict__ x,
                                                     const float* __restrict__ sx,
                                                     const float* __restrict__ P0,
                                                     const float* __restrict__ w_hh,
                                                     const float* __restrict__ b_ih,
                                                     const float* __restrict__ b_hh,
                                                     float* __restrict__ hout, int M) {
    int node = blockIdx.x * 4 + (threadIdx.x >> 6);
    if (node >= M) return;
    int d0 = (threadIdx.x & 63) * 4;
    float sxn = sx[node], xn = x[node];
    float4 r0 = *(const float4*)&P0[d0];
    float4 z0 = *(const float4*)&P0[256 + d0];
    float4 n0 = *(const float4*)&P0[512 + d0];
    float r1[4], z1[4], n1[4];
    #pragma unroll
    for (int j = 0; j < 4; j++) {
        r1[j] = w_hh[(size_t)(d0 + j) * D];
        z1[j] = w_hh[(size_t)(256 + d0 + j) * D];
        n1[j] = w_hh[(size_t)(512 + d0 + j) * D];
    }
    float4 bir = *(const float4*)&b_ih[d0];
    float4 biz = *(const float4*)&b_ih[256 + d0];
    float4 bin = *(const float4*)&b_ih[512 + d0];
    float4 bhr = *(const float4*)&b_hh[d0];
    float4 bhz = *(const float4*)&b_hh[256 + d0];
    float4 bhn = *(const float4*)&b_hh[512 + d0];
    float rr[4] = {sxn*r0.x + xn*r1[0] + bir.x + bhr.x, sxn*r0.y + xn*r1[1] + bir.y + bhr.y,
                   sxn*r0.z + xn*r1[2] + bir.z + bhr.z, sxn*r0.w + xn*r1[3] + bir.w + bhr.w};
    float zz[4] = {sxn*z0.x + xn*z1[0] + biz.x + bhz.x, sxn*z0.y + xn*z1[1] + biz.y + bhz.y,
                   sxn*z0.z + xn*z1[2] + biz.z + bhz.z, sxn*z0.w + xn*z1[3] + biz.w + bhz.w};
    float ni[4] = {sxn*n0.x + bin.x, sxn*n0.y + bin.y, sxn*n0.z + bin.z, sxn*n0.w + bin.w};
    float nh[4] = {xn*n1[0] + bhn.x, xn*n1[1] + bhn.y, xn*n1[2] + bhn.z, xn*n1[3] + bhn.w};
    float o[4];
    #pragma unroll
    for (int j = 0; j < 4; j++) {
        float r = sigm(rr[j]);
        float z = sigm(zz[j]);
        float nn = tanhf(ni[j] + r * nh[j]);
        float hp = (d0 + j == 0) ? xn : 0.f;
        o[j] = (1.f - z) * nn + z * hp;
    }
    *(float4*)&hout[(size_t)node * D + d0] = make_float4(o[0], o[1], o[2], o[3]);
}

// ---------------- gather + fused h2bf, 4-way ILP (runs after gru completes) ----------
__global__ __launch_bounds__(256) void gather_bf_kernel(const float* __restrict__ h,
                                                        const int* __restrict__ rowptr,
                                                        const int* __restrict__ esrc,
                                                        const float* __restrict__ eval,
                                                        unsigned short* __restrict__ A2, int n) {
    int node = (blockIdx.x * 256 + threadIdx.x) >> 6;
    int lane = threadIdx.x & 63;
    if (node >= n) return;
    int beg = rowptr[node], end = rowptr[node + 1];
    float4 ac0 = make_float4(0.f, 0.f, 0.f, 0.f);
    float4 ac1 = ac0, ac2 = ac0, ac3 = ac0;
    int e = beg;
    for (; e + 3 < end; e += 4) {
        int s0 = esrc[e], s1 = esrc[e + 1], s2 = esrc[e + 2], s3 = esrc[e + 3];
        float a0 = eval[e], a1 = eval[e + 1], a2 = eval[e + 2], a3 = eval[e + 3];
        float4 v0 = *(const float4*)&h[(size_t)s0 * D + lane * 4];
        float4 v1 = *(const float4*)&h[(size_t)s1 * D + lane * 4];
        float4 v2 = *(const float4*)&h[(size_t)s2 * D + lane * 4];
        float4 v3 = *(const float4*)&h[(size_t)s3 * D + lane * 4];
        ac0.x += a0 * v0.x; ac0.y += a0 * v0.y; ac0.z += a0 * v0.z; ac0.w += a0 * v0.w;
        ac1.x += a1 * v1.x; ac1.y += a1 * v1.y; ac1.z += a1 * v1.z; ac1.w += a1 * v1.w;
        ac2.x += a2 * v2.x; ac2.y += a2 * v2.y; ac2.z += a2 * v2.z; ac2.w += a2 * v2.w;
        ac3.x += a3 * v3.x; ac3.y += a3 * v3.y; ac3.z += a3 * v3.z; ac3.w += a3 * v3.w;
    }
    for (; e < end; e++) {
        int s0 = esrc[e];
        float a0 = eval[e];
        float4 v0 = *(const float4*)&h[(size_t)s0 * D + lane * 4];
        ac0.x += a0 * v0.x; ac0.y += a0 * v0.y; ac0.z += a0 * v0.z; ac0.w += a0 * v0.w;
    }
    float4 acc = make_float4((ac0.x + ac1.x) + (ac2.x + ac3.x),
                             (ac0.y + ac1.y) + (ac2.y + ac3.y),
                             (ac0.z + ac1.z) + (ac2.z + ac3.z),
                             (ac0.w + ac1.w) + (ac2.w + ac3.w));
    ushort4 hi = make_ushort4(f2bf(acc.x), f2bf(acc.y), f2bf(acc.z), f2bf(acc.w));
    ushort4 lo = make_ushort4(f2bf(acc.x - bf2f(hi.x)), f2bf(acc.y - bf2f(hi.y)),
                              f2bf(acc.z - bf2f(hi.z)), f2bf(acc.w - bf2f(hi.w)));
    *(ushort4*)&A2[(size_t)node * 1024 + lane * 4] = hi;
    *(ushort4*)&A2[(size_t)node * 1024 + 512 + lane * 4] = lo;
    float4 hv = *(const float4*)&h[(size_t)node * D + lane * 4];
    ushort4 hh = make_ushort4(f2bf(hv.x), f2bf(hv.y), f2bf(hv.z), f2bf(hv.w));
    ushort4 hl = make_ushort4(f2bf(hv.x - bf2f(hh.x)), f2bf(hv.y - bf2f(hh.y)),
                              f2bf(hv.z - bf2f(hh.z)), f2bf(hv.w - bf2f(hh.w)));
    *(ushort4*)&A2[(size_t)node * 1024 + 256 + lane * 4] = hh;
    *(ushort4*)&A2[(size_t)node * 1024 + 768 + lane * 4] = hl;
}

// ---------------- MFMA GRU v4 (R9-exact, proven 195us; NO setprio — R11 showed it costs 20%) ----
__global__ __launch_bounds__(256, 2) void gru_mfma_kernel(const unsigned short* __restrict__ A2,
                                                          const unsigned short* __restrict__ BT2,
                                                          const float* __restrict__ b_ih,
                                                          const float* __restrict__ b_hh,
                                                          float* __restrict__ h, int M) {
    __shared__ unsigned short sm[2][20480];   // 80 KB
    int tid = threadIdx.x;
    int lane = tid & 63;
    int wid = tid >> 6;
    int wr = wid >> 1, wc = wid & 1;

    // T1: bijective XCD swizzle — the 4 bnd-slices of slab g get bids {c, c+8, c+16, c+24}
    int bid = blockIdx.x;   // 0..1563
    int g, by;
    if (bid < 1536) {
        int ch = bid >> 5;
        int rem = bid & 31;
        g = ch * 8 + (rem & 7);
        by = rem >> 3;
    } else {
        int r = bid - 1536;
        g = 384 + (r >> 2);
        by = r & 3;
    }
    int bm = g * 128;
    int bnd = by * 64;

    // per-wave staging tables: 5 H0 frags + 5 H1 frags
    unsigned g0off[5], g1off[5];
    int slot0[5], slot1[5];
    bool g0A[5], g0G2[5], g1A[5], g1G2[5];
    #pragma unroll
    for (int i = 0; i < 5; i++) {
        int idx = wid * 5 + i;
        int f0 = (idx < 8) ? idx : idx + 8;        // H0: 0-7 (A_hi), 16-27 (B_hi)
        int f1 = (idx < 8) ? idx + 8 : idx + 20;   // H1: 8-15 (A_lo), 28-39 (B_lo)
        frag_addr(f0, bm, bnd, lane, g0off[i], g0A[i], g0G2[i]);
        frag_addr(f1, bm, bnd, lane, g1off[i], g1A[i], g1G2[i]);
        slot0[i] = f0; slot1[i] = f1;
    }

    f32x4 acc[4][8];
    #pragma unroll
    for (int i = 0; i < 4; i++)
        #pragma unroll
        for (int j = 0; j < 8; j++)
            acc[i][j] = (f32x4){0.f, 0.f, 0.f, 0.f};

    bf16x8 ah[4], al[4], bh[6], bl[6];

#define STAGE_H0(C_, B_)                                                           \
    { _Pragma("unroll")                                                            \
      for (int i = 0; i < 5; i++) {                                                \
        const unsigned short* gp = (g0A[i] ? A2 : BT2) + g0off[i]                  \
            + (C_) * 32 + ((g0G2[i] && (C_) >= 8) ? 262144u : 0u);                 \
        gload16(gp, &sm[B_][slot0[i] * 512]);                                      \
      } }
#define STAGE_H1(C_, B_)                                                           \
    { _Pragma("unroll")                                                            \
      for (int i = 0; i < 5; i++) {                                                \
        const unsigned short* gp = (g1A[i] ? A2 : BT2) + g1off[i]                  \
            + (C_) * 32 + ((g1G2[i] && (C_) >= 8) ? 262144u : 0u);                 \
        gload16(gp, &sm[B_][slot1[i] * 512]);                                      \
      } }

#define KBODY(C_, NIOFF_)                                                          \
    {   int cur = (C_) & 1;                                                        \
        asm volatile("s_waitcnt vmcnt(5)" ::: "memory");                           \
        __builtin_amdgcn_sched_barrier(0);                                         \
        __builtin_amdgcn_s_barrier();                                              \
        if ((C_) < 15) { STAGE_H0((C_) + 1, cur ^ 1); STAGE_H1((C_) + 1, cur ^ 1); } \
        _Pragma("unroll")                                                          \
        for (int m = 0; m < 4; m++)                                                \
            ah[m] = *(const bf16x8*)&sm[cur][(wr * 4 + m) * 512 + lane * 8];       \
        _Pragma("unroll")                                                          \
        for (int j = 0; j < 6; j++) {                                              \
            int fb = 16 + (j >> 1) * 4 + wc * 2 + (j & 1);                         \
            bh[j] = *(const bf16x8*)&sm[cur][fb * 512 + lane * 8];                 \
        }                                                                          \
        _Pragma("unroll")                                                          \
        for (int m = 0; m < 4; m++)                                                \
            _Pragma("unroll")                                                      \
            for (int j = 0; j < 6; j++) {                                          \
                int na = (j < 4) ? j : (NIOFF_) + (j & 1);                         \
                acc[m][na] = __builtin_amdgcn_mfma_f32_16x16x32_bf16(ah[m], bh[j], acc[m][na], 0, 0, 0); \
            }                                                                      \
        if ((C_) < 15) { asm volatile("s_waitcnt vmcnt(10)" ::: "memory"); }       \
        else           { asm volatile("s_waitcnt vmcnt(0)"  ::: "memory"); }       \
        __builtin_amdgcn_sched_barrier(0);                                         \
        __builtin_amdgcn_s_barrier();                                              \
        _Pragma("unroll")                                                          \
        for (int m = 0; m < 4; m++)                                                \
            al[m] = *(const bf16x8*)&sm[cur][(8 + wr * 4 + m) * 512 + lane * 8];   \
        _Pragma("unroll")                                                          \
        for (int j = 0; j < 6; j++) {                                              \
            int fb = 16 + (j >> 1) * 4 + wc * 2 + (j & 1);                         \
            bl[j] = *(const bf16x8*)&sm[cur][(fb + 12) * 512 + lane * 8];          \
        }                                                                          \
        _Pragma("unroll")                                                          \
        for (int m = 0; m < 4; m++)                                                \
            _Pragma("unroll")                                                      \
            for (int j = 0; j < 6; j++) {                                          \
                int na = (j < 4) ? j : (NIOFF_) + (j & 1);                         \
                acc[m][na] = __builtin_amdgcn_mfma_f32_16x16x32_bf16(al[m], bh[j], acc[m][na], 0, 0, 0); \
                acc[m][na] = __builtin_amdgcn_mfma_f32_16x16x32_bf16(ah[m], bl[j], acc[m][na], 0, 0, 0); \
            }                                                                      \
    }

    STAGE_H0(0, 0); STAGE_H1(0, 0);
    KBODY(0, 4)  KBODY(1, 4)  KBODY(2, 4)  KBODY(3, 4)
    KBODY(4, 4)  KBODY(5, 4)  KBODY(6, 4)  KBODY(7, 4)
    KBODY(8, 6)  KBODY(9, 6)  KBODY(10, 6) KBODY(11, 6)
    KBODY(12, 6) KBODY(13, 6) KBODY(14, 6) KBODY(15, 6)
#undef STAGE_H0
#undef STAGE_H1
#undef KBODY

    // epilogue: C layout col=lane&15, row=(lane>>4)*4+reg; writes fp32 h only
    int rbase = bm + wr * 64 + ((lane >> 4) << 2);
    #pragma unroll
    for (int jj = 0; jj < 2; jj++) {
        int d = bnd + (wc * 2 + jj) * 16 + (lane & 15);
        float cbr = b_ih[d] + b_hh[d];
        float cbz = b_ih[D + d] + b_hh[D + d];
        float bin = b_ih[2 * D + d];
        float bhn = b_hh[2 * D + d];
        #pragma unroll
        for (int m = 0; m < 4; m++) {
            #pragma unroll
            for (int q = 0; q < 4; q++) {
                int row = rbase + m * 16 + q;
                if (row < M) {
                    float r = sigm(acc[m][jj][q] + cbr);
                    float z = sigm(acc[m][2 + jj][q] + cbz);
                    float nn = tanhf(acc[m][4 + jj][q] + bin + r * (acc[m][6 + jj][q] + bhn));
                    float* hp = &h[(size_t)row * D + d];
                    float hv = *hp;
                    *hp = (1.f - z) * nn + z * hv;
                }
            }
        }
    }
}

// ---------------- readout + softmax (float4 hrow) ----------------
__global__ __launch_bounds__(256) void readout_kernel(const float* __restrict__ h,
                                                      const float* __restrict__ w_ro,
                                                      const float* __restrict__ b_ro,
                                                      float* __restrict__ out, int M) {
    __shared__ float ws_[D * K_OUT];
    for (int i = threadIdx.x; i < D * K_OUT; i += 256) ws_[i] = w_ro[i];
    __syncthreads();
    int group = threadIdx.x >> 5;
    int col   = threadIdx.x & 31;
    int node  = blockIdx.x * 8 + group;
    if (node >= M) return;
    float a0 = b_ro[col], a1 = 0.f, a2 = 0.f, a3 = 0.f;
    const float* hrow = &h[(size_t)node * D];
    #pragma unroll 4
    for (int k = 0; k < D; k += 4) {
        float4 hv = *(const float4*)&hrow[k];
        a0 += hv.x * ws_[(k + 0) * K_OUT + col];
        a1 += hv.y * ws_[(k + 1) * K_OUT + col];
        a2 += hv.z * ws_[(k + 2) * K_OUT + col];
        a3 += hv.w * ws_[(k + 3) * K_OUT + col];
    }
    float acc = (a0 + a1) + (a2 + a3);
    float mx = acc;
    #pragma unroll
    for (int off = 16; off > 0; off >>= 1) mx = fmaxf(mx, __shfl_xor(mx, off, 32));
    float e = __expf(acc - mx);
    float s = e;
    #pragma unroll
    for (int off = 16; off > 0; off >>= 1) s += __shfl_xor(s, off, 32);
    out[(size_t)node * K_OUT + col] = e / s;
}

extern "C" void kernel_launch(void* const* d_in, const int* in_sizes, int n_in,
                              void* d_out, int out_size, void* d_ws, size_t ws_size,
                              hipStream_t stream) {
    const float* x      = (const float*)d_in[0];
    const int*   ei     = (const int*)d_in[1];
    const float* ea     = (const float*)d_in[2];
    const float* weight = (const float*)d_in[3];
    const float* w_ih   = (const float*)d_in[4];
    const float* w_hh   = (const float*)d_in[5];
    const float* b_ih   = (const float*)d_in[6];
    const float* b_hh   = (const float*)d_in[7];
    const float* w_ro   = (const float*)d_in[8];
    const float* b_ro   = (const float*)d_in[9];
    float* out = (float*)d_out;

    int N = in_sizes[0];          // 50000
    int E = in_sizes[2];          // 800000
    const int* src = ei;
    const int* dst = ei + E;

    size_t ND = (size_t)N * D;
    float* h = (float*)d_ws;
    unsigned short* A2 = (unsigned short*)(h + ND);                      // NPAD x 1024 bf16
    float* P = (float*)(A2 + (size_t)NPAD * 1024);                       // 4 x 256 x 768
    unsigned short* BT2 = (unsigned short*)(P + (size_t)L_LAYERS * 256 * 768); // 4 x 1024 x 1024
    float* sx = (float*)(BT2 + (size_t)L_LAYERS * 1024 * 1024);
    int* cnt = (int*)(sx + N);
    int* rowptr = cnt + (N + 1);
    int* cursor = rowptr + (N + 1);
    int* esrc = cursor + (N + 1);
    float* eval = (float*)(esrc + E);

    // ---- CSR build ----
    hipMemsetAsync(cnt, 0, (N + 1) * sizeof(int), stream);
    hist_kernel<<<1024, 256, 0, stream>>>(dst, cnt, E);
    scan_kernel<<<1, 1024, 0, stream>>>(cnt, rowptr, cursor, N);
    reorder_kernel<<<1024, 256, 0, stream>>>(src, dst, ea, cursor, esrc, eval, E);

    // ---- weight precompute ----
    prep_wih_kernel<<<dim3(4, 12, 4), 256, 0, stream>>>(weight, w_ih, P);
    pack_bt2_kernel<<<16384, 256, 0, stream>>>(P, w_hh, BT2);

    // ---- layer 0 (rank-2) ----
    sgather_kernel<<<(N + 255) / 256, 256, 0, stream>>>(x, rowptr, esrc, eval, sx, N);
    layer0_kernel<<<(N + 3) / 4, 256, 0, stream>>>(x, sx, P, w_hh, b_ih, b_hh, h, N);

    // ---- layers 1..3 ----
    int nb = (NPAD / 128) * 4;    // 1564, 1D swizzled grid
    int gather_blocks = (N * 64 + 255) / 256;
    for (int l = 1; l < L_LAYERS; l++) {
        gather_bf_kernel<<<gather_blocks, 256, 0, stream>>>(h, rowptr, esrc, eval, A2, N);
        gru_mfma_kernel<<<nb, 256, 0, stream>>>(A2, BT2 + (size_t)l * 1024 * 1024,
                                                b_ih, b_hh, h, N);
    }
    readout_kernel<<<(N + 7) / 8, 256, 0, stream>>>(h, w_ro, b_ro, out, N);
}